// Round 7
// baseline (10451.124 us; speedup 1.0000x reference)
//
#include <hip/hip_runtime.h>
#include <stdint.h>
#include <stddef.h>
#include <math.h>

// ============================================================================
// Seq2SeqReinforce — persistent kernel, round 7: wave-local tick.
//  - same self-validating {seq,value} chunk protocol as round 6 (validated)
//  - NEW intra-tick structure: each dot's k-windows live in one 8-lane group
//    -> shfl_xor reduce; gates gathered by __shfl + cndmask select; each wave
//    owns 2 h-units end-to-end and publishes its chunks as soon as ready.
//  - ONE __syncthreads per tick (after chunk stage). No LDS partials/z arrays.
//  - hz uses per-wave tags hztag[NCL][4] (finishers span 4 waves).
// ============================================================================

#define PARTITIONABLE_PRNG 1   // bit-exact vs JAX, confirmed rounds 1-6

namespace s2sr {

constexpr int kV = 50257, kE = 256, kH = 256, kCc = 64, kB = 4, kT = 48;
constexpr int kZ = kH + kCc;   // 320
constexpr int kG = 4 * kH;     // 1024
constexpr int kMask = 103;
constexpr float kEps = 1e-5f;
constexpr float kTiny = 1.17549435e-38f;

constexpr int NWG = 256, TPB = 256;
constexpr int NCL = 32;                        // cluster WGs
constexpr int LEAD = 32;
constexpr int GANG0 = 33;
constexpr int NGANG = NWG - GANG0;             // 223
constexpr int RPW = (kV + NGANG - 1) / NGANG;  // 226 rows/WG
constexpr int NPX = 16;                        // gang WGs doing px0 duty

// LDS float offsets
constexpr int SH_STG = 0;     // 2 parities x 2 layers x 1024 = 4096 floats
constexpr int SH_TOT = 4608;  // (leader/gang reuse the same buffer)
// leader LDS offsets
constexpr int LD_ZIN = 0;     // 1280: fc1 input [b][320]
constexpr int LD_Z1  = 1280;  // 1280: fc1 out / LN result
constexpr int LD_CLS = 2560;  // 256:  cls cache [b][64]
constexpr int LD_LSE = 2816;  // 4
constexpr int LD_WPS = 2820;  // 16

struct alignas(128) Tag { unsigned v; unsigned _p[31]; };
struct alignas(128) GOut {
  unsigned long long key[kB];  // 32B
  float ps[kB];                // 16B
  unsigned tag;                // 4B
  unsigned _p[19];
};

struct SyncBlk {
  Tag ictr, igen;        // init barrier (RMW; init only)
  Tag ptok4[NPX][4];     // px0[t] per-wave tags (value t)
  Tag ztag4[4];          // z1n per-wave tags (value t)
  Tag etok4[4];          // xcur per-wave tags (value t)
  Tag hztag[NCL][4];     // hz per-cluster-WG per-WAVE tags (value hzt)
  GOut gout[NGANG];      // per-gang-WG sampling outputs
};

struct WS {
  // ---- zeroed head (memset each launch) ----
  SyncBlk s;
  unsigned long long hc[2][2][NCL][32];  // [slot][layer][wg][32]: {seq, float}
  float hzbuf[2][kB][kH];   // scan-boundary h1 (gated by hztag)
  float z1n[2][kB][kZ];     // LN output (gated by ztag4)
  float xcur[kB][kH];       // decoder x_t (gated by etok4)
  // ---- not zeroed (written before read, gated) ----
  float xd0[kB][kH];
  float px0[kT][kB][kG];
  float pxe[kT][kB][kG];
};

// ---------------- agent-scope helpers (LLC) ----------------
__device__ __forceinline__ float aldf(const float* p) {
  return __hip_atomic_load(p, __ATOMIC_RELAXED, __HIP_MEMORY_SCOPE_AGENT);
}
__device__ __forceinline__ void astf(float* p, float v) {
  __hip_atomic_store(p, v, __ATOMIC_RELAXED, __HIP_MEMORY_SCOPE_AGENT);
}
__device__ __forceinline__ unsigned ldu(const unsigned* p) {
  return __hip_atomic_load(p, __ATOMIC_RELAXED, __HIP_MEMORY_SCOPE_AGENT);
}
__device__ __forceinline__ unsigned long long ld64(const unsigned long long* p) {
  return __hip_atomic_load(p, __ATOMIC_RELAXED, __HIP_MEMORY_SCOPE_AGENT);
}
__device__ __forceinline__ void st64(unsigned long long* p, unsigned long long v) {
  __hip_atomic_store(p, v, __ATOMIC_RELAXED, __HIP_MEMORY_SCOPE_AGENT);
}
__device__ __forceinline__ void relTag(Tag* tg, unsigned v) {
  __hip_atomic_store(&tg->v, v, __ATOMIC_RELEASE, __HIP_MEMORY_SCOPE_AGENT);
}
// init barrier (startup only)
__device__ __forceinline__ void gbar(SyncBlk* sb, unsigned tgt) {
  __syncthreads();
  if (threadIdx.x == 0) {
    const unsigned old = __hip_atomic_fetch_add(&sb->ictr.v, 1u, __ATOMIC_RELEASE,
                                                __HIP_MEMORY_SCOPE_AGENT);
    if (old == tgt - 1u) relTag(&sb->igen, tgt);
    while (ldu(&sb->igen.v) < tgt) __builtin_amdgcn_s_sleep(2);
    __atomic_signal_fence(__ATOMIC_ACQUIRE);
  }
  __syncthreads();
}

// ---------------- Threefry2x32 (bit-exact vs JAX; validated) ----------------
__device__ __forceinline__ unsigned rotl32(unsigned v, int n) {
  return (v << n) | (v >> (32 - n));
}
__device__ __forceinline__ void tf2x32(unsigned k0, unsigned k1, unsigned x0, unsigned x1,
                                       unsigned& o0, unsigned& o1) {
  const unsigned k2 = k0 ^ k1 ^ 0x1BD11BDAu;
  unsigned v0 = x0 + k0, v1 = x1 + k1;
  v0 += v1; v1 = rotl32(v1, 13); v1 ^= v0;
  v0 += v1; v1 = rotl32(v1, 15); v1 ^= v0;
  v0 += v1; v1 = rotl32(v1, 26); v1 ^= v0;
  v0 += v1; v1 = rotl32(v1, 6);  v1 ^= v0;
  v0 += k1; v1 += k2 + 1u;
  v0 += v1; v1 = rotl32(v1, 17); v1 ^= v0;
  v0 += v1; v1 = rotl32(v1, 29); v1 ^= v0;
  v0 += v1; v1 = rotl32(v1, 16); v1 ^= v0;
  v0 += v1; v1 = rotl32(v1, 24); v1 ^= v0;
  v0 += k2; v1 += k0 + 2u;
  v0 += v1; v1 = rotl32(v1, 13); v1 ^= v0;
  v0 += v1; v1 = rotl32(v1, 15); v1 ^= v0;
  v0 += v1; v1 = rotl32(v1, 26); v1 ^= v0;
  v0 += v1; v1 = rotl32(v1, 6);  v1 ^= v0;
  v0 += k0; v1 += k1 + 3u;
  v0 += v1; v1 = rotl32(v1, 17); v1 ^= v0;
  v0 += v1; v1 = rotl32(v1, 29); v1 ^= v0;
  v0 += v1; v1 = rotl32(v1, 16); v1 ^= v0;
  v0 += v1; v1 = rotl32(v1, 24); v1 ^= v0;
  v0 += k1; v1 += k2 + 4u;
  v0 += v1; v1 = rotl32(v1, 13); v1 ^= v0;
  v0 += v1; v1 = rotl32(v1, 15); v1 ^= v0;
  v0 += v1; v1 = rotl32(v1, 26); v1 ^= v0;
  v0 += v1; v1 = rotl32(v1, 6);  v1 ^= v0;
  o0 = v0 + k2; o1 = v1 + k0 + 5u;
}
__device__ __forceinline__ unsigned rbits(unsigned k0, unsigned k1, unsigned i) {
#if PARTITIONABLE_PRNG
  unsigned a, b; tf2x32(k0, k1, 0u, i, a, b);
  return a ^ b;
#else
  constexpr unsigned HALF = (unsigned)((kB * kV + 1) / 2);
  unsigned a, b;
  if (i < HALF) { tf2x32(k0, k1, i, i + HALF, a, b); return a; }
  tf2x32(k0, k1, i - HALF, i, a, b); return b;
#endif
}
__device__ __forceinline__ float gumbel_from_bits(unsigned bits) {
  float f = __uint_as_float((bits >> 9) | 0x3f800000u) - 1.0f;
  f = fmaxf(f, kTiny);
  return -logf(-logf(f));
}
__device__ __forceinline__ unsigned ordkey(float f) {
  const unsigned u = __float_as_uint(f);
  return (u & 0x80000000u) ? ~u : (u | 0x80000000u);
}
__device__ __forceinline__ unsigned long long shflx64(unsigned long long v, int m) {
  unsigned lo = (unsigned)v, hi = (unsigned)(v >> 32);
  lo = (unsigned)__shfl_xor((int)lo, m, 64);
  hi = (unsigned)__shfl_xor((int)hi, m, 64);
  return ((unsigned long long)hi << 32) | (unsigned long long)lo;
}
__device__ __forceinline__ float sigm(float x) { return 1.0f / (1.0f + expf(-x)); }

// ---------------- wave-local LSTM tick ----------------
// Lane map: wave v = tid>>6, lane l = tid&63; row r = v*8 + (l>>3) (0..31),
// window w = l&7; grow = (r&3)*256 + cw*8 + (r>>2).
// Finishers: l<8 of each wave: u = v*2 + (l>>2), b = l&3.
template <bool STREAM>
__device__ __forceinline__ void lstm_tick(
    WS* ws, float* shf, int cw, int cc, bool do0, bool do1,
    const float* px, const float* pW0, const float* pW1,
    const float4* w0r, const float4* w1r,
    const float* bs0, const float* bs1,
    float& c0, float& c1, float& h0last, float& h1last,
    int w, bool fin, int fu, int fb, int hzt) {
  const int tid = (int)threadIdx.x;
  const int l = tid & 63;
  const int par = cc & 1;
  float pxg0 = 0.f, pxg1 = 0.f, pxg2 = 0.f, pxg3 = 0.f;
  if (do0 && fin) {   // 4 px loads, issued before the spin (overlap)
    const float* pb = px + fb * kG + cw * 8 + fu;
    pxg0 = aldf(pb);
    pxg1 = aldf(pb + 256);
    pxg2 = aldf(pb + 512);
    pxg3 = aldf(pb + 768);
  }
  // ---- consume 2048 chunks of tick cc-1 (4 h0 + 4 h1 per thread) ----
  {
    const unsigned long long* base = &ws->hc[(cc + 1) & 1][0][0][0];
    const unsigned expseq = (unsigned)cc;
    unsigned long long v[8];
#pragma unroll
    for (int k = 0; k < 4; ++k) v[k] = ld64(base + tid * 4 + k);
#pragma unroll
    for (int k = 0; k < 4; ++k) v[4 + k] = ld64(base + 1024 + tid * 4 + k);
    unsigned pend = 0;
#pragma unroll
    for (int k = 0; k < 8; ++k) if ((unsigned)v[k] != expseq) pend |= 1u << k;
    while (pend) {
#pragma unroll
      for (int k = 0; k < 8; ++k)
        if (pend & (1u << k))
          v[k] = ld64(base + (k < 4 ? tid * 4 + k : 1024 + tid * 4 + (k - 4)));
#pragma unroll
      for (int k = 0; k < 8; ++k)
        if ((unsigned)v[k] == expseq) pend &= ~(1u << k);
    }
#pragma unroll
    for (int k = 0; k < 4; ++k) {
      const int c = tid * 4 + k;
      const int s = c & 31;
      shf[SH_STG + par * 2048 + (s >> 3) * 256 + (c >> 5) * 8 + (s & 7)] =
          __uint_as_float((unsigned)(v[k] >> 32));
      shf[SH_STG + par * 2048 + 1024 + (s >> 3) * 256 + (c >> 5) * 8 + (s & 7)] =
          __uint_as_float((unsigned)(v[4 + k] >> 32));
    }
  }
  __syncthreads();   // the only barrier in the tick
  // ---- layer 0: dots + wave reduce + gather + finish + publish ----
  float zl0[4] = {0.f, 0.f, 0.f, 0.f};
  if (do0) {
    float4 wv0[8];
#pragma unroll
    for (int i = 0; i < 8; ++i)
      wv0[i] = STREAM ? *reinterpret_cast<const float4*>(pW0 + i * 4) : w0r[i];
    const float* A = &shf[SH_STG + par * 2048 + w * 32];
    float a0 = 0.f, a1 = 0.f, a2 = 0.f, a3 = 0.f;
#pragma unroll
    for (int i = 0; i < 8; ++i) {
      const float4 wv = wv0[i];
      const float4 x0 = *reinterpret_cast<const float4*>(A + 0 * 256 + i * 4);
      const float4 x1 = *reinterpret_cast<const float4*>(A + 1 * 256 + i * 4);
      const float4 x2 = *reinterpret_cast<const float4*>(A + 2 * 256 + i * 4);
      const float4 x3 = *reinterpret_cast<const float4*>(A + 3 * 256 + i * 4);
      a0 = fmaf(wv.x, x0.x, a0); a0 = fmaf(wv.y, x0.y, a0); a0 = fmaf(wv.z, x0.z, a0); a0 = fmaf(wv.w, x0.w, a0);
      a1 = fmaf(wv.x, x1.x, a1); a1 = fmaf(wv.y, x1.y, a1); a1 = fmaf(wv.z, x1.z, a1); a1 = fmaf(wv.w, x1.w, a1);
      a2 = fmaf(wv.x, x2.x, a2); a2 = fmaf(wv.y, x2.y, a2); a2 = fmaf(wv.z, x2.z, a2); a2 = fmaf(wv.w, x2.w, a2);
      a3 = fmaf(wv.x, x3.x, a3); a3 = fmaf(wv.y, x3.y, a3); a3 = fmaf(wv.z, x3.z, a3); a3 = fmaf(wv.w, x3.w, a3);
    }
#pragma unroll
    for (int m = 1; m < 8; m <<= 1) {
      a0 += __shfl_xor(a0, m, 64); a1 += __shfl_xor(a1, m, 64);
      a2 += __shfl_xor(a2, m, 64); a3 += __shfl_xor(a3, m, 64);
    }
#pragma unroll
    for (int g = 0; g < 4; ++g) {
      const int src = ((((l & 7) >> 2) * 4) + g) * 8;  // within-wave, <64
      const float s0 = __shfl(a0, src, 64);
      const float s1 = __shfl(a1, src, 64);
      const float s2 = __shfl(a2, src, 64);
      const float s3 = __shfl(a3, src, 64);
      zl0[g] = (fb == 0) ? s0 : (fb == 1) ? s1 : (fb == 2) ? s2 : s3;
    }
  }
  if (fin) {
    if (do0) {
      const float zi = zl0[0] + bs0[0] + pxg0;
      const float zf = zl0[1] + bs0[1] + pxg1;
      const float zg = zl0[2] + bs0[2] + pxg2;
      const float zo = zl0[3] + bs0[3] + pxg3;
      const float cn = sigm(zf) * c0 + sigm(zi) * tanhf(zg);
      h0last = sigm(zo) * tanhf(cn);
      c0 = cn;
    }
    st64(&ws->hc[cc & 1][0][cw][fb * 8 + fu],
         ((unsigned long long)__float_as_uint(h0last) << 32) |
         (unsigned long long)(unsigned)(cc + 1));
  }
  // ---- layer 1 ----
  float zl1[4] = {0.f, 0.f, 0.f, 0.f};
  if (do1) {
    float4 wv1[16];
#pragma unroll
    for (int i = 0; i < 16; ++i)
      wv1[i] = STREAM ? *reinterpret_cast<const float4*>(pW1 + i * 4) : w1r[i];
    const float* Bp = (w < 4) ? &shf[SH_STG + par * 2048 + w * 64]
                              : &shf[SH_STG + par * 2048 + 1024 + (w - 4) * 64];
    float a0 = 0.f, a1 = 0.f, a2 = 0.f, a3 = 0.f;
#pragma unroll
    for (int i = 0; i < 16; ++i) {
      const float4 wv = wv1[i];
      const float4 x0 = *reinterpret_cast<const float4*>(Bp + 0 * 256 + i * 4);
      const float4 x1 = *reinterpret_cast<const float4*>(Bp + 1 * 256 + i * 4);
      const float4 x2 = *reinterpret_cast<const float4*>(Bp + 2 * 256 + i * 4);
      const float4 x3 = *reinterpret_cast<const float4*>(Bp + 3 * 256 + i * 4);
      a0 = fmaf(wv.x, x0.x, a0); a0 = fmaf(wv.y, x0.y, a0); a0 = fmaf(wv.z, x0.z, a0); a0 = fmaf(wv.w, x0.w, a0);
      a1 = fmaf(wv.x, x1.x, a1); a1 = fmaf(wv.y, x1.y, a1); a1 = fmaf(wv.z, x1.z, a1); a1 = fmaf(wv.w, x1.w, a1);
      a2 = fmaf(wv.x, x2.x, a2); a2 = fmaf(wv.y, x2.y, a2); a2 = fmaf(wv.z, x2.z, a2); a2 = fmaf(wv.w, x2.w, a2);
      a3 = fmaf(wv.x, x3.x, a3); a3 = fmaf(wv.y, x3.y, a3); a3 = fmaf(wv.z, x3.z, a3); a3 = fmaf(wv.w, x3.w, a3);
    }
#pragma unroll
    for (int m = 1; m < 8; m <<= 1) {
      a0 += __shfl_xor(a0, m, 64); a1 += __shfl_xor(a1, m, 64);
      a2 += __shfl_xor(a2, m, 64); a3 += __shfl_xor(a3, m, 64);
    }
#pragma unroll
    for (int g = 0; g < 4; ++g) {
      const int src = ((((l & 7) >> 2) * 4) + g) * 8;
      const float s0 = __shfl(a0, src, 64);
      const float s1 = __shfl(a1, src, 64);
      const float s2 = __shfl(a2, src, 64);
      const float s3 = __shfl(a3, src, 64);
      zl1[g] = (fb == 0) ? s0 : (fb == 1) ? s1 : (fb == 2) ? s2 : s3;
    }
  }
  if (fin) {
    if (do1) {
      const float zi = zl1[0] + bs1[0];
      const float zf = zl1[1] + bs1[1];
      const float zg = zl1[2] + bs1[2];
      const float zo = zl1[3] + bs1[3];
      const float cn = sigm(zf) * c1 + sigm(zi) * tanhf(zg);
      h1last = sigm(zo) * tanhf(cn);
      c1 = cn;
    }
    st64(&ws->hc[cc & 1][1][cw][fb * 8 + fu],
         ((unsigned long long)__float_as_uint(h1last) << 32) |
         (unsigned long long)(unsigned)(cc + 1));
    if (hzt >= 0) astf(&ws->hzbuf[hzt & 1][fb][cw * 8 + fu], h1last);
  }
}

// ---------------- kernel ----------------
__global__ void __launch_bounds__(TPB, 1) s2s_kernel(
    const int* __restrict__ input_ids, const float* __restrict__ labels,
    const float* __restrict__ emb,
    const float* __restrict__ W_e2e, const float* __restrict__ b_e2e,
    const float* __restrict__ W_e2d, const float* __restrict__ b_e2d,
    const float* __restrict__ encWih, const float* __restrict__ encWhh,
    const float* __restrict__ encbih, const float* __restrict__ encbhh,
    const float* __restrict__ decWih, const float* __restrict__ decWhh,
    const float* __restrict__ decbih, const float* __restrict__ decbhh,
    const float* __restrict__ W_cls, const float* __restrict__ b_cls,
    const float* __restrict__ Wfc1, const float* __restrict__ bfc1,
    const float* __restrict__ lng, const float* __restrict__ lnb,
    const float* __restrict__ W_fc2, const float* __restrict__ b_fc2,
    float* __restrict__ out, WS* __restrict__ ws) {
  const int wg = (int)blockIdx.x;
  const int tid = (int)threadIdx.x;
  SyncBlk* sb = &ws->s;
  __shared__ __align__(16) float shf[SH_TOT];
  __shared__ unsigned long long shk[16];
  __shared__ int shi[8];

  // ================= init phase 1 =================
  if (wg < kB * kT) {
    const int b = wg / kT, j = wg % kT;
    const int id = input_ids[b * kT + j];
    for (int i = tid; i < kE; i += 256) shf[i] = emb[(size_t)id * kE + i];
    __syncthreads();
    const float* wr = W_e2e + (size_t)tid * kE;
    float acc = b_e2e[tid];
    for (int k = 0; k < kE; k += 4) {
      const float4 wv = *reinterpret_cast<const float4*>(wr + k);
      const float4 xv = *reinterpret_cast<const float4*>(&shf[k]);
      acc = fmaf(xv.x, wv.x, acc); acc = fmaf(xv.y, wv.y, acc);
      acc = fmaf(xv.z, wv.z, acc); acc = fmaf(xv.w, wv.w, acc);
    }
    __syncthreads();
    shf[256 + tid] = fmaxf(acc, 0.f);
  } else if (wg == 192) {
    if (tid < kB) {
      const int t0 = input_ids[tid * kT];
      out[tid * kT] = 0.f;
      out[kB * kT + tid * kT] = (float)t0;
    }
  } else if (wg == 193) {
    const float* wr = W_e2d + (size_t)tid * kE;
    const float* e0 = emb + (size_t)input_ids[0 * kT] * kE;
    const float* e1 = emb + (size_t)input_ids[1 * kT] * kE;
    const float* e2 = emb + (size_t)input_ids[2 * kT] * kE;
    const float* e3 = emb + (size_t)input_ids[3 * kT] * kE;
    const float bb = b_e2d[tid];
    float a0 = bb, a1 = bb, a2 = bb, a3 = bb;
    for (int k = 0; k < kE; k += 4) {
      const float4 wv = *reinterpret_cast<const float4*>(wr + k);
      const float4 v0 = *reinterpret_cast<const float4*>(e0 + k);
      const float4 v1 = *reinterpret_cast<const float4*>(e1 + k);
      const float4 v2 = *reinterpret_cast<const float4*>(e2 + k);
      const float4 v3 = *reinterpret_cast<const float4*>(e3 + k);
      a0 = fmaf(v0.x, wv.x, a0); a0 = fmaf(v0.y, wv.y, a0); a0 = fmaf(v0.z, wv.z, a0); a0 = fmaf(v0.w, wv.w, a0);
      a1 = fmaf(v1.x, wv.x, a1); a1 = fmaf(v1.y, wv.y, a1); a1 = fmaf(v1.z, wv.z, a1); a1 = fmaf(v1.w, wv.w, a1);
      a2 = fmaf(v2.x, wv.x, a2); a2 = fmaf(v2.y, wv.y, a2); a2 = fmaf(v2.z, wv.z, a2); a2 = fmaf(v2.w, wv.w, a2);
      a3 = fmaf(v3.x, wv.x, a3); a3 = fmaf(v3.y, wv.y, a3); a3 = fmaf(v3.z, wv.z, a3); a3 = fmaf(v3.w, wv.w, a3);
    }
    astf(&ws->xd0[0][tid], fmaxf(a0, 0.f));
    astf(&ws->xd0[1][tid], fmaxf(a1, 0.f));
    astf(&ws->xd0[2][tid], fmaxf(a2, 0.f));
    astf(&ws->xd0[3][tid], fmaxf(a3, 0.f));
  }
  gbar(sb, (unsigned)NWG);

  // ================= init phase 2 =================
  if (wg < kB * kT) {
    const int b = wg / kT, j = wg % kT;
#pragma unroll
    for (int rr = 0; rr < 4; ++rr) {
      const int g = rr * 256 + tid;
      const float* wr = encWih + (size_t)g * kH;
      float acc = 0.f;
      for (int k = 0; k < kH; k += 4) {
        const float4 wv = *reinterpret_cast<const float4*>(wr + k);
        const float4 xv = *reinterpret_cast<const float4*>(&shf[256 + k]);
        acc = fmaf(xv.x, wv.x, acc); acc = fmaf(xv.y, wv.y, acc);
        acc = fmaf(xv.z, wv.z, acc); acc = fmaf(xv.w, wv.w, acc);
      }
      astf(&ws->pxe[j][0][0] + (size_t)b * kG + g, acc);
    }
  } else if (wg >= 192 && wg < 208) {
    const int w2 = wg - 192, b = w2 >> 2, q = w2 & 3;
    const int g = q * 256 + tid;
    for (int i = tid; i < kH; i += 256) shf[i] = aldf(&ws->xd0[b][i]);
    __syncthreads();
    const float* wr = decWih + (size_t)g * kH;
    float acc = 0.f;
    for (int k = 0; k < kH; k += 4) {
      const float4 wv = *reinterpret_cast<const float4*>(wr + k);
      const float4 xv = *reinterpret_cast<const float4*>(&shf[k]);
      acc = fmaf(xv.x, wv.x, acc); acc = fmaf(xv.y, wv.y, acc);
      acc = fmaf(xv.z, wv.z, acc); acc = fmaf(xv.w, wv.w, acc);
    }
    astf(&ws->px0[0][0][0] + (size_t)b * kG + g, acc);
  }
  gbar(sb, (unsigned)(2 * NWG));

  // ================= roles =================
  if (wg < NCL) {
    // ---------------- cluster ----------------
    const int cw = wg;
    const int v = tid >> 6, l = tid & 63;
    const int r = v * 8 + (l >> 3);   // local row 0..31
    const int w = l & 7;              // k-window
    const int grow = (r & 3) * 256 + cw * 8 + (r >> 2);
    const bool fin = l < 8;
    const int fu = v * 2 + (l >> 2);  // unit (valid when fin)
    const int fb = l & 3;             // batch (valid when fin)
    float c0 = 0.f, c1 = 0.f, h0last = 0.f, h1last = 0.f;
    float bs0[4] = {0.f, 0.f, 0.f, 0.f}, bs1[4] = {0.f, 0.f, 0.f, 0.f};
    if (fin) {
#pragma unroll
      for (int g = 0; g < 4; ++g) {
        bs0[g] = encbih[g * 256 + cw * 8 + fu] + encbhh[g * 256 + cw * 8 + fu];
        bs1[g] = encbih[kG + g * 256 + cw * 8 + fu] + encbhh[kG + g * 256 + cw * 8 + fu];
      }
    }
    const float* pW0e = encWhh + (size_t)grow * kH + w * 32;
    const float* pW1e = (w < 4)
        ? encWih + (size_t)kG * kH + (size_t)grow * kH + w * 64
        : encWhh + (size_t)kG * kH + (size_t)grow * kH + (w - 4) * 64;
    int cc = 0;
    for (int j = 0; j < kT; ++j, ++cc)
      lstm_tick<true>(ws, shf, cw, cc, true, j > 0, &ws->pxe[j][0][0],
                      pW0e, pW1e, nullptr, nullptr, bs0, bs1,
                      c0, c1, h0last, h1last, w, fin, fu, fb, -1);
    lstm_tick<true>(ws, shf, cw, cc, false, true, nullptr,
                    pW0e, pW1e, nullptr, nullptr, bs0, bs1,
                    c0, c1, h0last, h1last, w, fin, fu, fb, -1);
    ++cc;
    // decoder weights -> registers
    float4 w0d[8], w1d[16];
    {
      const float* p0 = decWhh + (size_t)grow * kH + w * 32;
#pragma unroll
      for (int i = 0; i < 8; ++i) w0d[i] = *reinterpret_cast<const float4*>(p0 + i * 4);
      const float* p1 = (w < 4)
          ? decWih + (size_t)kG * kH + (size_t)grow * kH + w * 64
          : decWhh + (size_t)kG * kH + (size_t)grow * kH + (w - 4) * 64;
#pragma unroll
      for (int i = 0; i < 16; ++i) w1d[i] = *reinterpret_cast<const float4*>(p1 + i * 4);
      if (fin) {
#pragma unroll
        for (int g = 0; g < 4; ++g) {
          bs0[g] = decbih[g * 256 + cw * 8 + fu] + decbhh[g * 256 + cw * 8 + fu];
          bs1[g] = decbih[kG + g * 256 + cw * 8 + fu] + decbhh[kG + g * 256 + cw * 8 + fu];
        }
      }
    }
    for (int t = 1; t < kT; ++t) {
      for (int j = 0; j < t; ++j, ++cc) {
        const bool d1 = (j > 0) || (t >= 2);
        const int hzt = (j == 0 && t >= 2) ? (t - 1) : -1;
        if (j == t - 1 && t >= 2) {
          if (tid < 64) {
            Tag* p = &sb->ptok4[tid >> 2][tid & 3];
            while (ldu(&p->v) < (unsigned)(t - 1)) {}
            __atomic_signal_fence(__ATOMIC_ACQUIRE);
          }
          __syncthreads();
        }
        lstm_tick<false>(ws, shf, cw, cc, true, d1, &ws->px0[j][0][0],
                         nullptr, nullptr, w0d, w1d, bs0, bs1,
                         c0, c1, h0last, h1last, w, fin, fu, fb, hzt);
        if (hzt >= 0 && l == 0) relTag(&sb->hztag[cw][v], (unsigned)hzt);
      }
    }
    lstm_tick<false>(ws, shf, cw, cc, false, true, nullptr,
                     nullptr, nullptr, w0d, w1d, bs0, bs1,
                     c0, c1, h0last, h1last, w, fin, fu, fb, kT - 1);
    if (l == 0) relTag(&sb->hztag[cw][v], (unsigned)(kT - 1));
  } else if (wg == LEAD) {
    // ---------------- leader ----------------
    if (tid < kB * kCc) {
      const int b = tid >> 6, c = tid & 63;
      shf[LD_CLS + tid] = fmaf(labels[b], W_cls[c], b_cls[c]);
    }
    __syncthreads();
    for (int t = 1; t < kT; ++t) {
      if (tid < NCL * 4) {
        while (ldu(&sb->hztag[tid >> 2][tid & 3].v) < (unsigned)t)
          __builtin_amdgcn_s_sleep(1);
        __atomic_signal_fence(__ATOMIC_ACQUIRE);
      }
      __syncthreads();
      for (int i = tid; i < kB * kZ; i += 256) {
        const int b = i / kZ, k = i - b * kZ;
        shf[LD_ZIN + i] = (k < kH) ? aldf(&ws->hzbuf[t & 1][b][k])
                                   : shf[LD_CLS + b * kCc + (k - kH)];
      }
      __syncthreads();
#pragma unroll
      for (int rep = 0; rep < 5; ++rep) {
        const int task = tid + rep * 256;
        const int b = task / kZ, o = task - b * kZ;
        const float* wr = Wfc1 + (size_t)o * kZ;
        const float* zz = &shf[LD_ZIN + b * kZ];
        float acc = bfc1[o];
        for (int k = 0; k < kZ; k += 4) {
          const float4 wv = *reinterpret_cast<const float4*>(wr + k);
          const float4 zv = *reinterpret_cast<const float4*>(zz + k);
          acc = fmaf(zv.x, wv.x, acc); acc = fmaf(zv.y, wv.y, acc);
          acc = fmaf(zv.z, wv.z, acc); acc = fmaf(zv.w, wv.w, acc);
        }
        shf[LD_Z1 + task] = fmaxf(acc, 0.f);
      }
      __syncthreads();
      {
        const int b = tid >> 6, ln = tid & 63;
        float s1 = 0.f, s2 = 0.f;
        for (int i = ln; i < kZ; i += 64) {
          const float v2 = shf[LD_Z1 + b * kZ + i]; s1 += v2; s2 += v2 * v2;
        }
#pragma unroll
        for (int o = 32; o > 0; o >>= 1) { s1 += __shfl_xor(s1, o, 64); s2 += __shfl_xor(s2, o, 64); }
        const float mu = s1 * (1.0f / kZ);
        const float var = s2 * (1.0f / kZ) - mu * mu;
        const float rs = 1.0f / sqrtf(var + kEps);
        for (int i = ln; i < kZ; i += 64) {
          const float v2 = fmaf((shf[LD_Z1 + b * kZ + i] - mu) * rs, lng[i], lnb[i]);
          shf[LD_Z1 + b * kZ + i] = v2;
          astf(&ws->z1n[t & 1][b][i], v2);
        }
        if (ln == 0) relTag(&sb->ztag4[b], (unsigned)t);
      }
      if (tid < NGANG) {
        while (ldu(&sb->gout[tid].tag) < (unsigned)t) __builtin_amdgcn_s_sleep(2);
        __atomic_signal_fence(__ATOMIC_ACQUIRE);
      }
      __syncthreads();
      {
        unsigned long long kk[kB];
        float pp[kB];
        if (tid < NGANG) {
          const GOut* g = &sb->gout[tid];
#pragma unroll
          for (int b = 0; b < kB; ++b) { kk[b] = ld64(&g->key[b]); pp[b] = aldf(&g->ps[b]); }
        } else {
#pragma unroll
          for (int b = 0; b < kB; ++b) { kk[b] = 0ull; pp[b] = 0.f; }
        }
#pragma unroll
        for (int b = 0; b < kB; ++b) {
#pragma unroll
          for (int m = 1; m < 64; m <<= 1) {
            const unsigned long long ko = shflx64(kk[b], m);
            pp[b] += __shfl_xor(pp[b], m, 64);
            if (ko > kk[b]) kk[b] = ko;
          }
        }
        if ((tid & 63) == 0) {
          const int wv = tid >> 6;
#pragma unroll
          for (int b = 0; b < kB; ++b) { shk[wv * kB + b] = kk[b]; shf[LD_WPS + wv * kB + b] = pp[b]; }
        }
      }
      __syncthreads();
      if (tid < kB) {
        const int b = tid;
        unsigned long long key = shk[b];
        float s = shf[LD_WPS + b];
        for (int wv = 1; wv < 4; ++wv) {
          const unsigned long long ko = shk[wv * kB + b];
          if (ko > key) key = ko;
          s += shf[LD_WPS + wv * kB + b];
        }
        const int samp = (int)(0xFFFFFFFFu - (unsigned)(key & 0xFFFFFFFFull));
        const float lse = logf(s);
        const int cur = input_ids[b * kT + t];
        const int nxt = (cur == kMask) ? samp : cur;
        out[kB * kT + b * kT + t] = (float)nxt;
        shi[b] = nxt; shi[4 + b] = samp;
        shf[LD_LSE + b] = lse;
      }
      __syncthreads();
      if (t < kT - 1) {
        const float* wr = W_e2d + (size_t)tid * kE;
        const float* e0 = emb + (size_t)shi[0] * kE;
        const float* e1 = emb + (size_t)shi[1] * kE;
        const float* e2 = emb + (size_t)shi[2] * kE;
        const float* e3 = emb + (size_t)shi[3] * kE;
        const float bb = b_e2d[tid];
        float a0 = bb, a1 = bb, a2 = bb, a3 = bb;
        for (int k = 0; k < kE; k += 4) {
          const float4 wv = *reinterpret_cast<const float4*>(wr + k);
          const float4 v0 = *reinterpret_cast<const float4*>(e0 + k);
          const float4 v1 = *reinterpret_cast<const float4*>(e1 + k);
          const float4 v2 = *reinterpret_cast<const float4*>(e2 + k);
          const float4 v3 = *reinterpret_cast<const float4*>(e3 + k);
          a0 = fmaf(v0.x, wv.x, a0); a0 = fmaf(v0.y, wv.y, a0); a0 = fmaf(v0.z, wv.z, a0); a0 = fmaf(v0.w, wv.w, a0);
          a1 = fmaf(v1.x, wv.x, a1); a1 = fmaf(v1.y, wv.y, a1); a1 = fmaf(v1.z, wv.z, a1); a1 = fmaf(v1.w, wv.w, a1);
          a2 = fmaf(v2.x, wv.x, a2); a2 = fmaf(v2.y, wv.y, a2); a2 = fmaf(v2.z, wv.z, a2); a2 = fmaf(v2.w, wv.w, a2);
          a3 = fmaf(v3.x, wv.x, a3); a3 = fmaf(v3.y, wv.y, a3); a3 = fmaf(v3.z, wv.z, a3); a3 = fmaf(v3.w, wv.w, a3);
        }
        astf(&ws->xcur[0][tid], fmaxf(a0, 0.f));
        astf(&ws->xcur[1][tid], fmaxf(a1, 0.f));
        astf(&ws->xcur[2][tid], fmaxf(a2, 0.f));
        astf(&ws->xcur[3][tid], fmaxf(a3, 0.f));
        if ((tid & 63) == 0) relTag(&sb->etok4[tid >> 6], (unsigned)t);
      }
      {
        const int b = tid >> 6, lane = tid & 63;
        const int sp = shi[4 + b];
        const float* wr = W_fc2 + (size_t)sp * kZ;
        float acc = 0.f;
#pragma unroll
        for (int i = 0; i < 5; ++i)
          acc = fmaf(shf[LD_Z1 + b * kZ + lane + i * 64], wr[lane + i * 64], acc);
#pragma unroll
        for (int o = 32; o > 0; o >>= 1) acc += __shfl_xor(acc, o, 64);
        if (lane == 0) out[b * kT + t] = acc + b_fc2[sp] - shf[LD_LSE + b];
      }
      __syncthreads();
    }
  } else {
    // ---------------- gang ----------------
    const int gi = wg - GANG0;
    const int start = gi * RPW;
    const int cnt = (RPW < kV - start) ? RPW : (kV - start);
    const bool act = tid < cnt;
    const int row = start + tid;
    for (int t = 1; t < kT; ++t) {
      if (tid < 4) {
        while (ldu(&sb->ztag4[tid].v) < (unsigned)t) __builtin_amdgcn_s_sleep(16);
        __atomic_signal_fence(__ATOMIC_ACQUIRE);
      }
      __syncthreads();
      for (int i = tid; i < kB * kZ; i += 256) shf[i] = aldf(&ws->z1n[t & 1][0][0] + i);
      __syncthreads();
      unsigned fk0, fk1;
      tf2x32(0u, 1234u, 0u, (unsigned)t, fk0, fk1);
      float lv[kB] = {0.f, 0.f, 0.f, 0.f};
      if (act) {
        const float* wr = W_fc2 + (size_t)row * kZ;
        const float bb = b_fc2[row];
        float a0 = bb, a1 = bb, a2 = bb, a3 = bb;
        for (int k = 0; k < kZ; k += 4) {
          const float4 wv = *reinterpret_cast<const float4*>(wr + k);
          const float4 z0 = *reinterpret_cast<const float4*>(&shf[0 * kZ + k]);
          const float4 z1 = *reinterpret_cast<const float4*>(&shf[1 * kZ + k]);
          const float4 z2 = *reinterpret_cast<const float4*>(&shf[2 * kZ + k]);
          const float4 z3 = *reinterpret_cast<const float4*>(&shf[3 * kZ + k]);
          a0 = fmaf(z0.x, wv.x, a0); a0 = fmaf(z0.y, wv.y, a0); a0 = fmaf(z0.z, wv.z, a0); a0 = fmaf(z0.w, wv.w, a0);
          a1 = fmaf(z1.x, wv.x, a1); a1 = fmaf(z1.y, wv.y, a1); a1 = fmaf(z1.z, wv.z, a1); a1 = fmaf(z1.w, wv.w, a1);
          a2 = fmaf(z2.x, wv.x, a2); a2 = fmaf(z2.y, wv.y, a2); a2 = fmaf(z2.z, wv.z, a2); a2 = fmaf(z2.w, wv.w, a2);
          a3 = fmaf(z3.x, wv.x, a3); a3 = fmaf(z3.y, wv.y, a3); a3 = fmaf(z3.z, wv.z, a3); a3 = fmaf(z3.w, wv.w, a3);
        }
        lv[0] = a0; lv[1] = a1; lv[2] = a2; lv[3] = a3;
      }
#pragma unroll
      for (int b = 0; b < kB; ++b) {
        unsigned long long key = 0ull;
        float sv = 0.f;
        if (act) {
          const unsigned bits = rbits(fk0, fk1, (unsigned)(b * kV + row));
          const float pv = lv[b] + gumbel_from_bits(bits);
          key = ((unsigned long long)ordkey(pv) << 32) |
                (unsigned long long)(0xFFFFFFFFu - (unsigned)row);
          sv = expf(lv[b]);
        }
#pragma unroll
        for (int m = 1; m < 64; m <<= 1) {
          const unsigned long long ko = shflx64(key, m);
          sv += __shfl_xor(sv, m, 64);
          if (ko > key) key = ko;
        }
        if ((tid & 63) == 0) { shk[(tid >> 6) * kB + b] = key; shf[1408 + (tid >> 6) * kB + b] = sv; }
      }
      __syncthreads();
      if (tid == 0) {
        GOut* g = &sb->gout[gi];
#pragma unroll
        for (int b = 0; b < kB; ++b) {
          unsigned long long key = shk[b];
          float s = shf[1408 + b];
          for (int w2 = 1; w2 < 4; ++w2) {
            const unsigned long long ko = shk[w2 * kB + b];
            if (ko > key) key = ko;
            s += shf[1408 + w2 * kB + b];
          }
          st64(&g->key[b], key);
          astf(&g->ps[b], s);
        }
        __hip_atomic_store(&g->tag, (unsigned)t, __ATOMIC_RELEASE, __HIP_MEMORY_SCOPE_AGENT);
      }
      __syncthreads();
      if (gi < NPX && t < kT - 1) {
        if (tid < 4) {
          while (ldu(&sb->etok4[tid].v) < (unsigned)t) __builtin_amdgcn_s_sleep(8);
          __atomic_signal_fence(__ATOMIC_ACQUIRE);
        }
        __syncthreads();
        for (int i = tid; i < kB * kH; i += 256) shf[i] = aldf(&ws->xcur[0][0] + i);
        __syncthreads();
        {
          const int rowg = gi * 64 + (tid & 63), b = tid >> 6;
          const float* wr = decWih + (size_t)rowg * kH;
          const float* xz = &shf[b * kH];
          float acc = 0.f;
          for (int k = 0; k < kH; k += 4) {
            const float4 wv = *reinterpret_cast<const float4*>(wr + k);
            const float4 xv = *reinterpret_cast<const float4*>(xz + k);
            acc = fmaf(xv.x, wv.x, acc); acc = fmaf(xv.y, wv.y, acc);
            acc = fmaf(xv.z, wv.z, acc); acc = fmaf(xv.w, wv.w, acc);
          }
          astf(&ws->px0[t][0][0] + (size_t)b * kG + rowg, acc);
          if ((tid & 63) == 0) relTag(&sb->ptok4[gi][tid >> 6], (unsigned)t);
        }
      }
      __syncthreads();
    }
  }
}

} // namespace s2sr

extern "C" void kernel_launch(void* const* d_in, const int* in_sizes, int n_in,
                              void* d_out, int out_size, void* d_ws, size_t ws_size,
                              hipStream_t stream) {
  using namespace s2sr;
  (void)in_sizes; (void)n_in; (void)out_size;
  if (ws_size < sizeof(WS)) return;
  const int*   input_ids = (const int*)d_in[0];
  // d_in[1] = attention_mask (unused)
  const float* labels    = (const float*)d_in[2];
  const float* emb       = (const float*)d_in[3];
  const float* W_e2e     = (const float*)d_in[4];
  const float* b_e2e     = (const float*)d_in[5];
  const float* W_e2d     = (const float*)d_in[6];
  const float* b_e2d     = (const float*)d_in[7];
  const float* encWih    = (const float*)d_in[8];
  const float* encWhh    = (const float*)d_in[9];
  const float* encbih    = (const float*)d_in[10];
  const float* encbhh    = (const float*)d_in[11];
  const float* decWih    = (const float*)d_in[12];
  const float* decWhh    = (const float*)d_in[13];
  const float* decbih    = (const float*)d_in[14];
  const float* decbhh    = (const float*)d_in[15];
  const float* W_cls     = (const float*)d_in[16];
  const float* b_cls     = (const float*)d_in[17];
  const float* W_fc1     = (const float*)d_in[18];
  const float* b_fc1     = (const float*)d_in[19];
  const float* ln_g      = (const float*)d_in[20];
  const float* ln_b      = (const float*)d_in[21];
  const float* W_fc2     = (const float*)d_in[22];
  const float* b_fc2     = (const float*)d_in[23];

  // re-arm tags + zero chunk seqs
  hipMemsetAsync(d_ws, 0, (size_t)offsetof(WS, xd0), stream);
  hipLaunchKernelGGL(s2s_kernel, dim3(NWG), dim3(TPB), 0, stream,
      input_ids, labels, emb, W_e2e, b_e2e, W_e2d, b_e2d,
      encWih, encWhh, encbih, encbhh, decWih, decWhh, decbih, decbhh,
      W_cls, b_cls, W_fc1, b_fc1, ln_g, ln_b, W_fc2, b_fc2,
      (float*)d_out, (WS*)d_ws);
}

// Round 8
// 6968.829 us; speedup vs baseline: 1.4997x; 1.4997x over previous
//
#include <hip/hip_runtime.h>
#include <stdint.h>
#include <stddef.h>
#include <math.h>

// ============================================================================
// Seq2SeqReinforce — persistent kernel, round 8: split-phase dataflow tick.
//  - r6's proven self-validating {seq,value} chunk protocol, reorganized:
//    Phase A = l0 only (consume h0 chunks -> dots -> reduce -> PUBLISH h0
//    mid-tick); Phase B = l1 (consume h1 chunks published a tick ago ->
//    dots -> publish h1/hz). Only Phase A is on the cross-WG critical path.
//  - chunk layout idx = b*256+h matches LDS layout -> coalesced, conflict-free
//    unpack (fixes r6's 8.1M LDS bank conflicts; r7's 344M shuffle disaster
//    reverted entirely).
//  - both rings (h0 via Phase-A chain, h1 via Phase-B chain) keep the <=2-tick
//    skew bound: each phase consumes before publishing within the same phase.
// ============================================================================

#define PARTITIONABLE_PRNG 1   // bit-exact vs JAX, confirmed rounds 1-7

namespace s2sr {

constexpr int kV = 50257, kE = 256, kH = 256, kCc = 64, kB = 4, kT = 48;
constexpr int kZ = kH + kCc;   // 320
constexpr int kG = 4 * kH;     // 1024
constexpr int kMask = 103;
constexpr float kEps = 1e-5f;
constexpr float kTiny = 1.17549435e-38f;

constexpr int NWG = 256, TPB = 256;
constexpr int NCL = 32;                        // cluster WGs
constexpr int LEAD = 32;
constexpr int GANG0 = 33;
constexpr int NGANG = NWG - GANG0;             // 223
constexpr int RPW = (kV + NGANG - 1) / NGANG;  // 226 rows/WG
constexpr int NPX = 16;                        // gang WGs doing px0 duty

// LDS float offsets (cluster tick layout)
constexpr int SH_H0 = 0;      // 1024: staged h0(cc-1) [b][256]
constexpr int SH_H1 = 1024;   // 1024: staged h1(cc-2) [b][256]
constexpr int SH_P0 = 2048;   // 1024: l0 partials [w][32][4]
constexpr int SH_P1 = 3072;   // 1024: l1 partials
constexpr int SH_TOT = 4608;
// leader LDS offsets
constexpr int LD_ZIN = 0;     // 1280: fc1 input [b][320]
constexpr int LD_Z1  = 1280;  // 1280: fc1 out / LN result
constexpr int LD_CLS = 2560;  // 256:  cls cache [b][64]
constexpr int LD_LSE = 2816;  // 4
constexpr int LD_WPS = 2820;  // 16

struct alignas(128) Tag { unsigned v; unsigned _p[31]; };
struct alignas(128) GOut {
  unsigned long long key[kB];  // 32B
  float ps[kB];                // 16B
  unsigned tag;                // 4B
  unsigned _p[19];
};

struct SyncBlk {
  Tag ictr, igen;        // init barrier (RMW; init only)
  Tag ptok4[NPX][4];     // px0[t] per-wave tags (value t)
  Tag ztag4[4];          // z1n per-wave tags (value t)
  Tag etok4[4];          // xcur per-wave tags (value t)
  Tag hztag[NCL];        // hz per-WG tags (wave-0 stores + wave-0 release)
  GOut gout[NGANG];      // per-gang-WG sampling outputs
};

struct WS {
  // ---- zeroed head (memset each launch) ----
  SyncBlk s;
  unsigned long long hc0[2][kB * kH];  // [slot][b*256+h]: {seq in lo32, val in hi32}
  unsigned long long hc1[2][kB * kH];
  float hzbuf[2][kB][kH];   // scan-boundary h1 (gated by hztag)
  float z1n[2][kB][kZ];     // LN output (gated by ztag4)
  float xcur[kB][kH];       // decoder x_t (gated by etok4)
  // ---- not zeroed (written before read, gated) ----
  float xd0[kB][kH];
  float px0[kT][kB][kG];
  float pxe[kT][kB][kG];
};

// ---------------- agent-scope helpers (LLC) ----------------
__device__ __forceinline__ float aldf(const float* p) {
  return __hip_atomic_load(p, __ATOMIC_RELAXED, __HIP_MEMORY_SCOPE_AGENT);
}
__device__ __forceinline__ void astf(float* p, float v) {
  __hip_atomic_store(p, v, __ATOMIC_RELAXED, __HIP_MEMORY_SCOPE_AGENT);
}
__device__ __forceinline__ unsigned ldu(const unsigned* p) {
  return __hip_atomic_load(p, __ATOMIC_RELAXED, __HIP_MEMORY_SCOPE_AGENT);
}
__device__ __forceinline__ unsigned long long ld64(const unsigned long long* p) {
  return __hip_atomic_load(p, __ATOMIC_RELAXED, __HIP_MEMORY_SCOPE_AGENT);
}
__device__ __forceinline__ void st64(unsigned long long* p, unsigned long long v) {
  __hip_atomic_store(p, v, __ATOMIC_RELAXED, __HIP_MEMORY_SCOPE_AGENT);
}
__device__ __forceinline__ void relTag(Tag* tg, unsigned v) {
  __hip_atomic_store(&tg->v, v, __ATOMIC_RELEASE, __HIP_MEMORY_SCOPE_AGENT);
}
// init barrier (startup only)
__device__ __forceinline__ void gbar(SyncBlk* sb, unsigned tgt) {
  __syncthreads();
  if (threadIdx.x == 0) {
    const unsigned old = __hip_atomic_fetch_add(&sb->ictr.v, 1u, __ATOMIC_RELEASE,
                                                __HIP_MEMORY_SCOPE_AGENT);
    if (old == tgt - 1u) relTag(&sb->igen, tgt);
    while (ldu(&sb->igen.v) < tgt) __builtin_amdgcn_s_sleep(2);
    __atomic_signal_fence(__ATOMIC_ACQUIRE);
  }
  __syncthreads();
}

// ---------------- Threefry2x32 (bit-exact vs JAX; validated) ----------------
__device__ __forceinline__ unsigned rotl32(unsigned v, int n) {
  return (v << n) | (v >> (32 - n));
}
__device__ __forceinline__ void tf2x32(unsigned k0, unsigned k1, unsigned x0, unsigned x1,
                                       unsigned& o0, unsigned& o1) {
  const unsigned k2 = k0 ^ k1 ^ 0x1BD11BDAu;
  unsigned v0 = x0 + k0, v1 = x1 + k1;
  v0 += v1; v1 = rotl32(v1, 13); v1 ^= v0;
  v0 += v1; v1 = rotl32(v1, 15); v1 ^= v0;
  v0 += v1; v1 = rotl32(v1, 26); v1 ^= v0;
  v0 += v1; v1 = rotl32(v1, 6);  v1 ^= v0;
  v0 += k1; v1 += k2 + 1u;
  v0 += v1; v1 = rotl32(v1, 17); v1 ^= v0;
  v0 += v1; v1 = rotl32(v1, 29); v1 ^= v0;
  v0 += v1; v1 = rotl32(v1, 16); v1 ^= v0;
  v0 += v1; v1 = rotl32(v1, 24); v1 ^= v0;
  v0 += k2; v1 += k0 + 2u;
  v0 += v1; v1 = rotl32(v1, 13); v1 ^= v0;
  v0 += v1; v1 = rotl32(v1, 15); v1 ^= v0;
  v0 += v1; v1 = rotl32(v1, 26); v1 ^= v0;
  v0 += v1; v1 = rotl32(v1, 6);  v1 ^= v0;
  v0 += k0; v1 += k1 + 3u;
  v0 += v1; v1 = rotl32(v1, 17); v1 ^= v0;
  v0 += v1; v1 = rotl32(v1, 29); v1 ^= v0;
  v0 += v1; v1 = rotl32(v1, 16); v1 ^= v0;
  v0 += v1; v1 = rotl32(v1, 24); v1 ^= v0;
  v0 += k1; v1 += k2 + 4u;
  v0 += v1; v1 = rotl32(v1, 13); v1 ^= v0;
  v0 += v1; v1 = rotl32(v1, 15); v1 ^= v0;
  v0 += v1; v1 = rotl32(v1, 26); v1 ^= v0;
  v0 += v1; v1 = rotl32(v1, 6);  v1 ^= v0;
  o0 = v0 + k2; o1 = v1 + k0 + 5u;
}
__device__ __forceinline__ unsigned rbits(unsigned k0, unsigned k1, unsigned i) {
#if PARTITIONABLE_PRNG
  unsigned a, b; tf2x32(k0, k1, 0u, i, a, b);
  return a ^ b;
#else
  constexpr unsigned HALF = (unsigned)((kB * kV + 1) / 2);
  unsigned a, b;
  if (i < HALF) { tf2x32(k0, k1, i, i + HALF, a, b); return a; }
  tf2x32(k0, k1, i - HALF, i, a, b); return b;
#endif
}
__device__ __forceinline__ float gumbel_from_bits(unsigned bits) {
  float f = __uint_as_float((bits >> 9) | 0x3f800000u) - 1.0f;
  f = fmaxf(f, kTiny);
  return -logf(-logf(f));
}
__device__ __forceinline__ unsigned ordkey(float f) {
  const unsigned u = __float_as_uint(f);
  return (u & 0x80000000u) ? ~u : (u | 0x80000000u);
}
__device__ __forceinline__ unsigned long long shflx64(unsigned long long v, int m) {
  unsigned lo = (unsigned)v, hi = (unsigned)(v >> 32);
  lo = (unsigned)__shfl_xor((int)lo, m, 64);
  hi = (unsigned)__shfl_xor((int)hi, m, 64);
  return ((unsigned long long)hi << 32) | (unsigned long long)lo;
}
__device__ __forceinline__ float sigm(float x) { return 1.0f / (1.0f + expf(-x)); }

// ---------------- split-phase LSTM tick ----------------
// Dot map (r6): r = tid&31 (local row: gate g=r&3, unit u=r>>2), w = tid>>5.
// grow = (r&3)*256 + cw*8 + (r>>2). Finishers: tid<32 -> fu=tid>>2, fb=tid&3.
// Chunk index = b*256 + h  (== LDS layout index).
template <bool STREAM>
__device__ __forceinline__ void lstm_tick(
    WS* ws, float* shf, int cw, int cc, bool do0, bool do1,
    const float* px, const float* pW0, const float* pW1,
    const float4* w0r, const float4* w1r,
    const float* bs0, const float* bs1,
    float& c0, float& c1, float& h0last, float& h1last,
    int w, int r, bool fin, int fu, int fb, int hzt) {
  const int tid = (int)threadIdx.x;
  float pxg0 = 0.f, pxg1 = 0.f, pxg2 = 0.f, pxg3 = 0.f;
  if (do0 && fin) {   // px prefetch before the spin (overlaps detect)
    const float* pb = px + fb * kG + cw * 8 + fu;
    pxg0 = aldf(pb);
    pxg1 = aldf(pb + 256);
    pxg2 = aldf(pb + 512);
    pxg3 = aldf(pb + 768);
  }
  // ======== Phase A : layer 0 (critical path) ========
  {
    const unsigned long long* base = &ws->hc0[(cc + 1) & 1][0];
    const unsigned expseq = (unsigned)cc;
    unsigned long long v[4];
#pragma unroll
    for (int k = 0; k < 4; ++k) v[k] = ld64(base + tid + k * 256);
    unsigned pend = 0;
#pragma unroll
    for (int k = 0; k < 4; ++k) if ((unsigned)v[k] != expseq) pend |= 1u << k;
    while (pend) {
#pragma unroll
      for (int k = 0; k < 4; ++k)
        if (pend & (1u << k)) v[k] = ld64(base + tid + k * 256);
#pragma unroll
      for (int k = 0; k < 4; ++k)
        if ((unsigned)v[k] == expseq) pend &= ~(1u << k);
    }
#pragma unroll
    for (int k = 0; k < 4; ++k)
      shf[SH_H0 + tid + k * 256] = __uint_as_float((unsigned)(v[k] >> 32));
  }
  __syncthreads();
  if (do0) {
    float4 wv0[8];
#pragma unroll
    for (int i = 0; i < 8; ++i)
      wv0[i] = STREAM ? *reinterpret_cast<const float4*>(pW0 + i * 4) : w0r[i];
    const float* A = &shf[SH_H0 + w * 32];
    float a0 = 0.f, a1 = 0.f, a2 = 0.f, a3 = 0.f;
#pragma unroll
    for (int i = 0; i < 8; ++i) {
      const float4 wv = wv0[i];
      const float4 x0 = *reinterpret_cast<const float4*>(A + 0 * 256 + i * 4);
      const float4 x1 = *reinterpret_cast<const float4*>(A + 1 * 256 + i * 4);
      const float4 x2 = *reinterpret_cast<const float4*>(A + 2 * 256 + i * 4);
      const float4 x3 = *reinterpret_cast<const float4*>(A + 3 * 256 + i * 4);
      a0 = fmaf(wv.x, x0.x, a0); a0 = fmaf(wv.y, x0.y, a0); a0 = fmaf(wv.z, x0.z, a0); a0 = fmaf(wv.w, x0.w, a0);
      a1 = fmaf(wv.x, x1.x, a1); a1 = fmaf(wv.y, x1.y, a1); a1 = fmaf(wv.z, x1.z, a1); a1 = fmaf(wv.w, x1.w, a1);
      a2 = fmaf(wv.x, x2.x, a2); a2 = fmaf(wv.y, x2.y, a2); a2 = fmaf(wv.z, x2.z, a2); a2 = fmaf(wv.w, x2.w, a2);
      a3 = fmaf(wv.x, x3.x, a3); a3 = fmaf(wv.y, x3.y, a3); a3 = fmaf(wv.z, x3.z, a3); a3 = fmaf(wv.w, x3.w, a3);
    }
    *reinterpret_cast<float4*>(&shf[SH_P0 + w * 128 + r * 4]) = float4{a0, a1, a2, a3};
  }
  __syncthreads();
  if (fin) {
    float hn = h0last;
    if (do0) {
      float z[4];
#pragma unroll
      for (int g = 0; g < 4; ++g) {
        const int base2 = SH_P0 + (fu * 4 + g) * 4 + fb;
        z[g] = shf[base2 + 0 * 128] + shf[base2 + 1 * 128] + shf[base2 + 2 * 128] +
               shf[base2 + 3 * 128] + shf[base2 + 4 * 128] + shf[base2 + 5 * 128] +
               shf[base2 + 6 * 128] + shf[base2 + 7 * 128] + bs0[g];
      }
      z[0] += pxg0; z[1] += pxg1; z[2] += pxg2; z[3] += pxg3;
      const float cn = sigm(z[1]) * c0 + sigm(z[0]) * tanhf(z[2]);
      hn = sigm(z[3]) * tanhf(cn);
      c0 = cn;
    }
    h0last = hn;
    st64(&ws->hc0[cc & 1][fb * 256 + cw * 8 + fu],
         ((unsigned long long)__float_as_uint(hn) << 32) |
         (unsigned long long)(unsigned)(cc + 1));   // EARLY publish
  }
  // ======== Phase B : layer 1 (off critical path) ========
  {
    const unsigned long long* base = &ws->hc1[(cc + 1) & 1][0];
    const unsigned expseq = (unsigned)cc;
    unsigned long long v[4];
#pragma unroll
    for (int k = 0; k < 4; ++k) v[k] = ld64(base + tid + k * 256);
    unsigned pend = 0;
#pragma unroll
    for (int k = 0; k < 4; ++k) if ((unsigned)v[k] != expseq) pend |= 1u << k;
    while (pend) {
#pragma unroll
      for (int k = 0; k < 4; ++k)
        if (pend & (1u << k)) v[k] = ld64(base + tid + k * 256);
#pragma unroll
      for (int k = 0; k < 4; ++k)
        if ((unsigned)v[k] == expseq) pend &= ~(1u << k);
    }
#pragma unroll
    for (int k = 0; k < 4; ++k)
      shf[SH_H1 + tid + k * 256] = __uint_as_float((unsigned)(v[k] >> 32));
  }
  __syncthreads();
  if (do1) {
    float4 wv1[16];
#pragma unroll
    for (int i = 0; i < 16; ++i)
      wv1[i] = STREAM ? *reinterpret_cast<const float4*>(pW1 + i * 4) : w1r[i];
    const float* Bp = (w < 4) ? &shf[SH_H0 + w * 64] : &shf[SH_H1 + (w - 4) * 64];
    float a0 = 0.f, a1 = 0.f, a2 = 0.f, a3 = 0.f;
#pragma unroll
    for (int i = 0; i < 16; ++i) {
      const float4 wv = wv1[i];
      const float4 x0 = *reinterpret_cast<const float4*>(Bp + 0 * 256 + i * 4);
      const float4 x1 = *reinterpret_cast<const float4*>(Bp + 1 * 256 + i * 4);
      const float4 x2 = *reinterpret_cast<const float4*>(Bp + 2 * 256 + i * 4);
      const float4 x3 = *reinterpret_cast<const float4*>(Bp + 3 * 256 + i * 4);
      a0 = fmaf(wv.x, x0.x, a0); a0 = fmaf(wv.y, x0.y, a0); a0 = fmaf(wv.z, x0.z, a0); a0 = fmaf(wv.w, x0.w, a0);
      a1 = fmaf(wv.x, x1.x, a1); a1 = fmaf(wv.y, x1.y, a1); a1 = fmaf(wv.z, x1.z, a1); a1 = fmaf(wv.w, x1.w, a1);
      a2 = fmaf(wv.x, x2.x, a2); a2 = fmaf(wv.y, x2.y, a2); a2 = fmaf(wv.z, x2.z, a2); a2 = fmaf(wv.w, x2.w, a2);
      a3 = fmaf(wv.x, x3.x, a3); a3 = fmaf(wv.y, x3.y, a3); a3 = fmaf(wv.z, x3.z, a3); a3 = fmaf(wv.w, x3.w, a3);
    }
    *reinterpret_cast<float4*>(&shf[SH_P1 + w * 128 + r * 4]) = float4{a0, a1, a2, a3};
  }
  __syncthreads();
  if (fin) {
    float hn = h1last;
    if (do1) {
      float z[4];
#pragma unroll
      for (int g = 0; g < 4; ++g) {
        const int base2 = SH_P1 + (fu * 4 + g) * 4 + fb;
        z[g] = shf[base2 + 0 * 128] + shf[base2 + 1 * 128] + shf[base2 + 2 * 128] +
               shf[base2 + 3 * 128] + shf[base2 + 4 * 128] + shf[base2 + 5 * 128] +
               shf[base2 + 6 * 128] + shf[base2 + 7 * 128] + bs1[g];
      }
      const float cn = sigm(z[1]) * c1 + sigm(z[0]) * tanhf(z[2]);
      hn = sigm(z[3]) * tanhf(cn);
      c1 = cn;
    }
    h1last = hn;
    st64(&ws->hc1[cc & 1][fb * 256 + cw * 8 + fu],
         ((unsigned long long)__float_as_uint(hn) << 32) |
         (unsigned long long)(unsigned)(cc + 1));
    if (hzt >= 0) astf(&ws->hzbuf[hzt & 1][fb][cw * 8 + fu], hn);
  }
}

// ---------------- kernel ----------------
__global__ void __launch_bounds__(TPB, 1) s2s_kernel(
    const int* __restrict__ input_ids, const float* __restrict__ labels,
    const float* __restrict__ emb,
    const float* __restrict__ W_e2e, const float* __restrict__ b_e2e,
    const float* __restrict__ W_e2d, const float* __restrict__ b_e2d,
    const float* __restrict__ encWih, const float* __restrict__ encWhh,
    const float* __restrict__ encbih, const float* __restrict__ encbhh,
    const float* __restrict__ decWih, const float* __restrict__ decWhh,
    const float* __restrict__ decbih, const float* __restrict__ decbhh,
    const float* __restrict__ W_cls, const float* __restrict__ b_cls,
    const float* __restrict__ Wfc1, const float* __restrict__ bfc1,
    const float* __restrict__ lng, const float* __restrict__ lnb,
    const float* __restrict__ W_fc2, const float* __restrict__ b_fc2,
    float* __restrict__ out, WS* __restrict__ ws) {
  const int wg = (int)blockIdx.x;
  const int tid = (int)threadIdx.x;
  SyncBlk* sb = &ws->s;
  __shared__ __align__(16) float shf[SH_TOT];
  __shared__ unsigned long long shk[16];
  __shared__ int shi[8];

  // ================= init phase 1 =================
  if (wg < kB * kT) {
    const int b = wg / kT, j = wg % kT;
    const int id = input_ids[b * kT + j];
    for (int i = tid; i < kE; i += 256) shf[i] = emb[(size_t)id * kE + i];
    __syncthreads();
    const float* wr = W_e2e + (size_t)tid * kE;
    float acc = b_e2e[tid];
    for (int k = 0; k < kE; k += 4) {
      const float4 wv = *reinterpret_cast<const float4*>(wr + k);
      const float4 xv = *reinterpret_cast<const float4*>(&shf[k]);
      acc = fmaf(xv.x, wv.x, acc); acc = fmaf(xv.y, wv.y, acc);
      acc = fmaf(xv.z, wv.z, acc); acc = fmaf(xv.w, wv.w, acc);
    }
    __syncthreads();
    shf[256 + tid] = fmaxf(acc, 0.f);
  } else if (wg == 192) {
    if (tid < kB) {
      const int t0 = input_ids[tid * kT];
      out[tid * kT] = 0.f;
      out[kB * kT + tid * kT] = (float)t0;
    }
  } else if (wg == 193) {
    const float* wr = W_e2d + (size_t)tid * kE;
    const float* e0 = emb + (size_t)input_ids[0 * kT] * kE;
    const float* e1 = emb + (size_t)input_ids[1 * kT] * kE;
    const float* e2 = emb + (size_t)input_ids[2 * kT] * kE;
    const float* e3 = emb + (size_t)input_ids[3 * kT] * kE;
    const float bb = b_e2d[tid];
    float a0 = bb, a1 = bb, a2 = bb, a3 = bb;
    for (int k = 0; k < kE; k += 4) {
      const float4 wv = *reinterpret_cast<const float4*>(wr + k);
      const float4 v0 = *reinterpret_cast<const float4*>(e0 + k);
      const float4 v1 = *reinterpret_cast<const float4*>(e1 + k);
      const float4 v2 = *reinterpret_cast<const float4*>(e2 + k);
      const float4 v3 = *reinterpret_cast<const float4*>(e3 + k);
      a0 = fmaf(v0.x, wv.x, a0); a0 = fmaf(v0.y, wv.y, a0); a0 = fmaf(v0.z, wv.z, a0); a0 = fmaf(v0.w, wv.w, a0);
      a1 = fmaf(v1.x, wv.x, a1); a1 = fmaf(v1.y, wv.y, a1); a1 = fmaf(v1.z, wv.z, a1); a1 = fmaf(v1.w, wv.w, a1);
      a2 = fmaf(v2.x, wv.x, a2); a2 = fmaf(v2.y, wv.y, a2); a2 = fmaf(v2.z, wv.z, a2); a2 = fmaf(v2.w, wv.w, a2);
      a3 = fmaf(v3.x, wv.x, a3); a3 = fmaf(v3.y, wv.y, a3); a3 = fmaf(v3.z, wv.z, a3); a3 = fmaf(v3.w, wv.w, a3);
    }
    astf(&ws->xd0[0][tid], fmaxf(a0, 0.f));
    astf(&ws->xd0[1][tid], fmaxf(a1, 0.f));
    astf(&ws->xd0[2][tid], fmaxf(a2, 0.f));
    astf(&ws->xd0[3][tid], fmaxf(a3, 0.f));
  }
  gbar(sb, (unsigned)NWG);

  // ================= init phase 2 =================
  if (wg < kB * kT) {
    const int b = wg / kT, j = wg % kT;
#pragma unroll
    for (int rr = 0; rr < 4; ++rr) {
      const int g = rr * 256 + tid;
      const float* wr = encWih + (size_t)g * kH;
      float acc = 0.f;
      for (int k = 0; k < kH; k += 4) {
        const float4 wv = *reinterpret_cast<const float4*>(wr + k);
        const float4 xv = *reinterpret_cast<const float4*>(&shf[256 + k]);
        acc = fmaf(xv.x, wv.x, acc); acc = fmaf(xv.y, wv.y, acc);
        acc = fmaf(xv.z, wv.z, acc); acc = fmaf(xv.w, wv.w, acc);
      }
      astf(&ws->pxe[j][0][0] + (size_t)b * kG + g, acc);
    }
  } else if (wg >= 192 && wg < 208) {
    const int w2 = wg - 192, b = w2 >> 2, q = w2 & 3;
    const int g = q * 256 + tid;
    for (int i = tid; i < kH; i += 256) shf[i] = aldf(&ws->xd0[b][i]);
    __syncthreads();
    const float* wr = decWih + (size_t)g * kH;
    float acc = 0.f;
    for (int k = 0; k < kH; k += 4) {
      const float4 wv = *reinterpret_cast<const float4*>(wr + k);
      const float4 xv = *reinterpret_cast<const float4*>(&shf[k]);
      acc = fmaf(xv.x, wv.x, acc); acc = fmaf(xv.y, wv.y, acc);
      acc = fmaf(xv.z, wv.z, acc); acc = fmaf(xv.w, wv.w, acc);
    }
    astf(&ws->px0[0][0][0] + (size_t)b * kG + g, acc);
  }
  gbar(sb, (unsigned)(2 * NWG));

  // ================= roles =================
  if (wg < NCL) {
    // ---------------- cluster ----------------
    const int cw = wg;
    const int r = tid & 31, w = tid >> 5;
    const int grow = (r & 3) * 256 + cw * 8 + (r >> 2);
    const bool fin = tid < 32;
    const int fu = tid >> 2, fb = tid & 3;   // valid when fin
    float c0 = 0.f, c1 = 0.f, h0last = 0.f, h1last = 0.f;
    float bs0[4] = {0.f, 0.f, 0.f, 0.f}, bs1[4] = {0.f, 0.f, 0.f, 0.f};
    if (fin) {
#pragma unroll
      for (int g = 0; g < 4; ++g) {
        bs0[g] = encbih[g * 256 + cw * 8 + fu] + encbhh[g * 256 + cw * 8 + fu];
        bs1[g] = encbih[kG + g * 256 + cw * 8 + fu] + encbhh[kG + g * 256 + cw * 8 + fu];
      }
    }
    const float* pW0e = encWhh + (size_t)grow * kH + w * 32;
    const float* pW1e = (w < 4)
        ? encWih + (size_t)kG * kH + (size_t)grow * kH + w * 64
        : encWhh + (size_t)kG * kH + (size_t)grow * kH + (w - 4) * 64;
    int cc = 0;
    for (int j = 0; j < kT; ++j, ++cc)
      lstm_tick<true>(ws, shf, cw, cc, true, j > 0, &ws->pxe[j][0][0],
                      pW0e, pW1e, nullptr, nullptr, bs0, bs1,
                      c0, c1, h0last, h1last, w, r, fin, fu, fb, -1);
    lstm_tick<true>(ws, shf, cw, cc, false, true, nullptr,
                    pW0e, pW1e, nullptr, nullptr, bs0, bs1,
                    c0, c1, h0last, h1last, w, r, fin, fu, fb, -1);
    ++cc;
    // decoder weights -> registers
    float4 w0d[8], w1d[16];
    {
      const float* p0 = decWhh + (size_t)grow * kH + w * 32;
#pragma unroll
      for (int i = 0; i < 8; ++i) w0d[i] = *reinterpret_cast<const float4*>(p0 + i * 4);
      const float* p1 = (w < 4)
          ? decWih + (size_t)kG * kH + (size_t)grow * kH + w * 64
          : decWhh + (size_t)kG * kH + (size_t)grow * kH + (w - 4) * 64;
#pragma unroll
      for (int i = 0; i < 16; ++i) w1d[i] = *reinterpret_cast<const float4*>(p1 + i * 4);
      if (fin) {
#pragma unroll
        for (int g = 0; g < 4; ++g) {
          bs0[g] = decbih[g * 256 + cw * 8 + fu] + decbhh[g * 256 + cw * 8 + fu];
          bs1[g] = decbih[kG + g * 256 + cw * 8 + fu] + decbhh[kG + g * 256 + cw * 8 + fu];
        }
      }
    }
    for (int t = 1; t < kT; ++t) {
      for (int j = 0; j < t; ++j, ++cc) {
        const bool d1 = (j > 0) || (t >= 2);
        const int hzt = (j == 0 && t >= 2) ? (t - 1) : -1;
        if (j == t - 1 && t >= 2) {
          if (tid < 64) {
            Tag* p = &sb->ptok4[tid >> 2][tid & 3];
            while (ldu(&p->v) < (unsigned)(t - 1)) {}
            __atomic_signal_fence(__ATOMIC_ACQUIRE);
          }
          __syncthreads();
        }
        lstm_tick<false>(ws, shf, cw, cc, true, d1, &ws->px0[j][0][0],
                         nullptr, nullptr, w0d, w1d, bs0, bs1,
                         c0, c1, h0last, h1last, w, r, fin, fu, fb, hzt);
        if (hzt >= 0 && tid == 0) relTag(&sb->hztag[cw], (unsigned)hzt);
      }
    }
    lstm_tick<false>(ws, shf, cw, cc, false, true, nullptr,
                     nullptr, nullptr, w0d, w1d, bs0, bs1,
                     c0, c1, h0last, h1last, w, r, fin, fu, fb, kT - 1);
    if (tid == 0) relTag(&sb->hztag[cw], (unsigned)(kT - 1));
  } else if (wg == LEAD) {
    // ---------------- leader ----------------
    if (tid < kB * kCc) {
      const int b = tid >> 6, c = tid & 63;
      shf[LD_CLS + tid] = fmaf(labels[b], W_cls[c], b_cls[c]);
    }
    __syncthreads();
    for (int t = 1; t < kT; ++t) {
      if (tid < NCL) {
        while (ldu(&sb->hztag[tid].v) < (unsigned)t) __builtin_amdgcn_s_sleep(1);
        __atomic_signal_fence(__ATOMIC_ACQUIRE);
      }
      __syncthreads();
      for (int i = tid; i < kB * kZ; i += 256) {
        const int b = i / kZ, k = i - b * kZ;
        shf[LD_ZIN + i] = (k < kH) ? aldf(&ws->hzbuf[t & 1][b][k])
                                   : shf[LD_CLS + b * kCc + (k - kH)];
      }
      __syncthreads();
#pragma unroll
      for (int rep = 0; rep < 5; ++rep) {
        const int task = tid + rep * 256;
        const int b = task / kZ, o = task - b * kZ;
        const float* wr = Wfc1 + (size_t)o * kZ;
        const float* zz = &shf[LD_ZIN + b * kZ];
        float acc = bfc1[o];
        for (int k = 0; k < kZ; k += 4) {
          const float4 wv = *reinterpret_cast<const float4*>(wr + k);
          const float4 zv = *reinterpret_cast<const float4*>(zz + k);
          acc = fmaf(zv.x, wv.x, acc); acc = fmaf(zv.y, wv.y, acc);
          acc = fmaf(zv.z, wv.z, acc); acc = fmaf(zv.w, wv.w, acc);
        }
        shf[LD_Z1 + task] = fmaxf(acc, 0.f);
      }
      __syncthreads();
      {
        const int b = tid >> 6, ln = tid & 63;
        float s1 = 0.f, s2 = 0.f;
        for (int i = ln; i < kZ; i += 64) {
          const float v2 = shf[LD_Z1 + b * kZ + i]; s1 += v2; s2 += v2 * v2;
        }
#pragma unroll
        for (int o = 32; o > 0; o >>= 1) { s1 += __shfl_xor(s1, o, 64); s2 += __shfl_xor(s2, o, 64); }
        const float mu = s1 * (1.0f / kZ);
        const float var = s2 * (1.0f / kZ) - mu * mu;
        const float rs = 1.0f / sqrtf(var + kEps);
        for (int i = ln; i < kZ; i += 64) {
          const float v2 = fmaf((shf[LD_Z1 + b * kZ + i] - mu) * rs, lng[i], lnb[i]);
          shf[LD_Z1 + b * kZ + i] = v2;
          astf(&ws->z1n[t & 1][b][i], v2);
        }
        if (ln == 0) relTag(&sb->ztag4[b], (unsigned)t);
      }
      if (tid < NGANG) {
        while (ldu(&sb->gout[tid].tag) < (unsigned)t) __builtin_amdgcn_s_sleep(2);
        __atomic_signal_fence(__ATOMIC_ACQUIRE);
      }
      __syncthreads();
      {
        unsigned long long kk[kB];
        float pp[kB];
        if (tid < NGANG) {
          const GOut* g = &sb->gout[tid];
#pragma unroll
          for (int b = 0; b < kB; ++b) { kk[b] = ld64(&g->key[b]); pp[b] = aldf(&g->ps[b]); }
        } else {
#pragma unroll
          for (int b = 0; b < kB; ++b) { kk[b] = 0ull; pp[b] = 0.f; }
        }
#pragma unroll
        for (int b = 0; b < kB; ++b) {
#pragma unroll
          for (int m = 1; m < 64; m <<= 1) {
            const unsigned long long ko = shflx64(kk[b], m);
            pp[b] += __shfl_xor(pp[b], m, 64);
            if (ko > kk[b]) kk[b] = ko;
          }
        }
        if ((tid & 63) == 0) {
          const int wv = tid >> 6;
#pragma unroll
          for (int b = 0; b < kB; ++b) { shk[wv * kB + b] = kk[b]; shf[LD_WPS + wv * kB + b] = pp[b]; }
        }
      }
      __syncthreads();
      if (tid < kB) {
        const int b = tid;
        unsigned long long key = shk[b];
        float s = shf[LD_WPS + b];
        for (int wv = 1; wv < 4; ++wv) {
          const unsigned long long ko = shk[wv * kB + b];
          if (ko > key) key = ko;
          s += shf[LD_WPS + wv * kB + b];
        }
        const int samp = (int)(0xFFFFFFFFu - (unsigned)(key & 0xFFFFFFFFull));
        const float lse = logf(s);
        const int cur = input_ids[b * kT + t];
        const int nxt = (cur == kMask) ? samp : cur;
        out[kB * kT + b * kT + t] = (float)nxt;
        shi[b] = nxt; shi[4 + b] = samp;
        shf[LD_LSE + b] = lse;
      }
      __syncthreads();
      if (t < kT - 1) {
        const float* wr = W_e2d + (size_t)tid * kE;
        const float* e0 = emb + (size_t)shi[0] * kE;
        const float* e1 = emb + (size_t)shi[1] * kE;
        const float* e2 = emb + (size_t)shi[2] * kE;
        const float* e3 = emb + (size_t)shi[3] * kE;
        const float bb = b_e2d[tid];
        float a0 = bb, a1 = bb, a2 = bb, a3 = bb;
        for (int k = 0; k < kE; k += 4) {
          const float4 wv = *reinterpret_cast<const float4*>(wr + k);
          const float4 v0 = *reinterpret_cast<const float4*>(e0 + k);
          const float4 v1 = *reinterpret_cast<const float4*>(e1 + k);
          const float4 v2 = *reinterpret_cast<const float4*>(e2 + k);
          const float4 v3 = *reinterpret_cast<const float4*>(e3 + k);
          a0 = fmaf(v0.x, wv.x, a0); a0 = fmaf(v0.y, wv.y, a0); a0 = fmaf(v0.z, wv.z, a0); a0 = fmaf(v0.w, wv.w, a0);
          a1 = fmaf(v1.x, wv.x, a1); a1 = fmaf(v1.y, wv.y, a1); a1 = fmaf(v1.z, wv.z, a1); a1 = fmaf(v1.w, wv.w, a1);
          a2 = fmaf(v2.x, wv.x, a2); a2 = fmaf(v2.y, wv.y, a2); a2 = fmaf(v2.z, wv.z, a2); a2 = fmaf(v2.w, wv.w, a2);
          a3 = fmaf(v3.x, wv.x, a3); a3 = fmaf(v3.y, wv.y, a3); a3 = fmaf(v3.z, wv.z, a3); a3 = fmaf(v3.w, wv.w, a3);
        }
        astf(&ws->xcur[0][tid], fmaxf(a0, 0.f));
        astf(&ws->xcur[1][tid], fmaxf(a1, 0.f));
        astf(&ws->xcur[2][tid], fmaxf(a2, 0.f));
        astf(&ws->xcur[3][tid], fmaxf(a3, 0.f));
        if ((tid & 63) == 0) relTag(&sb->etok4[tid >> 6], (unsigned)t);
      }
      {
        const int b = tid >> 6, lane = tid & 63;
        const int sp = shi[4 + b];
        const float* wr = W_fc2 + (size_t)sp * kZ;
        float acc = 0.f;
#pragma unroll
        for (int i = 0; i < 5; ++i)
          acc = fmaf(shf[LD_Z1 + b * kZ + lane + i * 64], wr[lane + i * 64], acc);
#pragma unroll
        for (int o = 32; o > 0; o >>= 1) acc += __shfl_xor(acc, o, 64);
        if (lane == 0) out[b * kT + t] = acc + b_fc2[sp] - shf[LD_LSE + b];
      }
      __syncthreads();
    }
  } else {
    // ---------------- gang ----------------
    const int gi = wg - GANG0;
    const int start = gi * RPW;
    const int cnt = (RPW < kV - start) ? RPW : (kV - start);
    const bool act = tid < cnt;
    const int row = start + tid;
    for (int t = 1; t < kT; ++t) {
      if (tid < 4) {
        while (ldu(&sb->ztag4[tid].v) < (unsigned)t) __builtin_amdgcn_s_sleep(16);
        __atomic_signal_fence(__ATOMIC_ACQUIRE);
      }
      __syncthreads();
      for (int i = tid; i < kB * kZ; i += 256) shf[i] = aldf(&ws->z1n[t & 1][0][0] + i);
      __syncthreads();
      unsigned fk0, fk1;
      tf2x32(0u, 1234u, 0u, (unsigned)t, fk0, fk1);
      float lv[kB] = {0.f, 0.f, 0.f, 0.f};
      if (act) {
        const float* wr = W_fc2 + (size_t)row * kZ;
        const float bb = b_fc2[row];
        float a0 = bb, a1 = bb, a2 = bb, a3 = bb;
        for (int k = 0; k < kZ; k += 4) {
          const float4 wv = *reinterpret_cast<const float4*>(wr + k);
          const float4 z0 = *reinterpret_cast<const float4*>(&shf[0 * kZ + k]);
          const float4 z1 = *reinterpret_cast<const float4*>(&shf[1 * kZ + k]);
          const float4 z2 = *reinterpret_cast<const float4*>(&shf[2 * kZ + k]);
          const float4 z3 = *reinterpret_cast<const float4*>(&shf[3 * kZ + k]);
          a0 = fmaf(z0.x, wv.x, a0); a0 = fmaf(z0.y, wv.y, a0); a0 = fmaf(z0.z, wv.z, a0); a0 = fmaf(z0.w, wv.w, a0);
          a1 = fmaf(z1.x, wv.x, a1); a1 = fmaf(z1.y, wv.y, a1); a1 = fmaf(z1.z, wv.z, a1); a1 = fmaf(z1.w, wv.w, a1);
          a2 = fmaf(z2.x, wv.x, a2); a2 = fmaf(z2.y, wv.y, a2); a2 = fmaf(z2.z, wv.z, a2); a2 = fmaf(z2.w, wv.w, a2);
          a3 = fmaf(z3.x, wv.x, a3); a3 = fmaf(z3.y, wv.y, a3); a3 = fmaf(z3.z, wv.z, a3); a3 = fmaf(z3.w, wv.w, a3);
        }
        lv[0] = a0; lv[1] = a1; lv[2] = a2; lv[3] = a3;
      }
#pragma unroll
      for (int b = 0; b < kB; ++b) {
        unsigned long long key = 0ull;
        float sv = 0.f;
        if (act) {
          const unsigned bits = rbits(fk0, fk1, (unsigned)(b * kV + row));
          const float pv = lv[b] + gumbel_from_bits(bits);
          key = ((unsigned long long)ordkey(pv) << 32) |
                (unsigned long long)(0xFFFFFFFFu - (unsigned)row);
          sv = expf(lv[b]);
        }
#pragma unroll
        for (int m = 1; m < 64; m <<= 1) {
          const unsigned long long ko = shflx64(key, m);
          sv += __shfl_xor(sv, m, 64);
          if (ko > key) key = ko;
        }
        if ((tid & 63) == 0) { shk[(tid >> 6) * kB + b] = key; shf[1408 + (tid >> 6) * kB + b] = sv; }
      }
      __syncthreads();
      if (tid == 0) {
        GOut* g = &sb->gout[gi];
#pragma unroll
        for (int b = 0; b < kB; ++b) {
          unsigned long long key = shk[b];
          float s = shf[1408 + b];
          for (int w2 = 1; w2 < 4; ++w2) {
            const unsigned long long ko = shk[w2 * kB + b];
            if (ko > key) key = ko;
            s += shf[1408 + w2 * kB + b];
          }
          st64(&g->key[b], key);
          astf(&g->ps[b], s);
        }
        __hip_atomic_store(&g->tag, (unsigned)t, __ATOMIC_RELEASE, __HIP_MEMORY_SCOPE_AGENT);
      }
      __syncthreads();
      if (gi < NPX && t < kT - 1) {
        if (tid < 4) {
          while (ldu(&sb->etok4[tid].v) < (unsigned)t) __builtin_amdgcn_s_sleep(8);
          __atomic_signal_fence(__ATOMIC_ACQUIRE);
        }
        __syncthreads();
        for (int i = tid; i < kB * kH; i += 256) shf[i] = aldf(&ws->xcur[0][0] + i);
        __syncthreads();
        {
          const int rowg = gi * 64 + (tid & 63), b = tid >> 6;
          const float* wr = decWih + (size_t)rowg * kH;
          const float* xz = &shf[b * kH];
          float acc = 0.f;
          for (int k = 0; k < kH; k += 4) {
            const float4 wv = *reinterpret_cast<const float4*>(wr + k);
            const float4 xv = *reinterpret_cast<const float4*>(xz + k);
            acc = fmaf(xv.x, wv.x, acc); acc = fmaf(xv.y, wv.y, acc);
            acc = fmaf(xv.z, wv.z, acc); acc = fmaf(xv.w, wv.w, acc);
          }
          astf(&ws->px0[t][0][0] + (size_t)b * kG + rowg, acc);
          if ((tid & 63) == 0) relTag(&sb->ptok4[gi][tid >> 6], (unsigned)t);
        }
      }
      __syncthreads();
    }
  }
}

} // namespace s2sr

extern "C" void kernel_launch(void* const* d_in, const int* in_sizes, int n_in,
                              void* d_out, int out_size, void* d_ws, size_t ws_size,
                              hipStream_t stream) {
  using namespace s2sr;
  (void)in_sizes; (void)n_in; (void)out_size;
  if (ws_size < sizeof(WS)) return;
  const int*   input_ids = (const int*)d_in[0];
  // d_in[1] = attention_mask (unused)
  const float* labels    = (const float*)d_in[2];
  const float* emb       = (const float*)d_in[3];
  const float* W_e2e     = (const float*)d_in[4];
  const float* b_e2e     = (const float*)d_in[5];
  const float* W_e2d     = (const float*)d_in[6];
  const float* b_e2d     = (const float*)d_in[7];
  const float* encWih    = (const float*)d_in[8];
  const float* encWhh    = (const float*)d_in[9];
  const float* encbih    = (const float*)d_in[10];
  const float* encbhh    = (const float*)d_in[11];
  const float* decWih    = (const float*)d_in[12];
  const float* decWhh    = (const float*)d_in[13];
  const float* decbih    = (const float*)d_in[14];
  const float* decbhh    = (const float*)d_in[15];
  const float* W_cls     = (const float*)d_in[16];
  const float* b_cls     = (const float*)d_in[17];
  const float* W_fc1     = (const float*)d_in[18];
  const float* b_fc1     = (const float*)d_in[19];
  const float* ln_g      = (const float*)d_in[20];
  const float* ln_b      = (const float*)d_in[21];
  const float* W_fc2     = (const float*)d_in[22];
  const float* b_fc2     = (const float*)d_in[23];

  // re-arm tags + zero chunk seqs
  hipMemsetAsync(d_ws, 0, (size_t)offsetof(WS, xd0), stream);
  hipLaunchKernelGGL(s2s_kernel, dim3(NWG), dim3(TPB), 0, stream,
      input_ids, labels, emb, W_e2e, b_e2e, W_e2d, b_e2d,
      encWih, encWhh, encbih, encbhh, decWih, decWhh, decbih, decbhh,
      W_cls, b_cls, W_fc1, b_fc1, ln_g, ln_b, W_fc2, b_fc2,
      (float*)d_out, (WS*)d_ws);
}